// Round 1
// baseline (101.437 us; speedup 1.0000x reference)
//
#include <hip/hip_runtime.h>

// DescLayer fused kernel for MI355X (gfx950).
// out[b,s,i] = res[b,s,i] + Nk[b,s,i]
//   ln   = LayerNorm(x) * gamma + beta          (biased var, eps inside sqrt)
//   xp   = ln @ M^T ; res = ln @ R^T            (M,R are [out,in] row-major)
//   Nk_i = sum_{j,g} P[i,j,g] * xp[j] * cos(2*pi*k / periods[i,j,g])
//
// One block (256 threads) per (b,s) row. Phase A: wave0 LayerNorm.
// Phase B: threads 0..127 do the two 64x64 matvecs (float4 loads).
// Phase C: 4 threads per output i, each covering 16 j * 8 g = 128 cos terms,
//          combined with two shfl_xor steps. Transcendental/L2 bound.

constexpr int BATCH = 2;
constexpr int SEQ   = 512;
constexpr int DIM   = 64;
constexpr int NB    = 8;
constexpr int ROWS  = BATCH * SEQ;
constexpr float LN_EPS   = 1e-5f;
constexpr float TWO_PI_F = 6.28318530717958647692f;

__global__ __launch_bounds__(256) void desc_fused(
    const float* __restrict__ x,
    const int*   __restrict__ kk,
    const float* __restrict__ M,
    const float* __restrict__ R,
    const float* __restrict__ P,
    const float* __restrict__ gamma,
    const float* __restrict__ beta,
    const float* __restrict__ periods,
    float* __restrict__ out)
{
    const int row = blockIdx.x;   // b*SEQ + s
    const int t   = threadIdx.x;  // 0..255

    __shared__ float ln_s[DIM];
    __shared__ float xp_s[DIM];
    __shared__ float res_s[DIM];

    // ---- Phase A: LayerNorm (wave 0, lanes 0..63) ----
    if (t < DIM) {
        float xv = x[row * DIM + t];
        float s1 = xv, s2 = xv * xv;
        #pragma unroll
        for (int off = 32; off > 0; off >>= 1) {
            s1 += __shfl_xor(s1, off, 64);
            s2 += __shfl_xor(s2, off, 64);
        }
        float mu  = s1 * (1.0f / DIM);
        float var = s2 * (1.0f / DIM) - mu * mu;   // biased variance
        ln_s[t] = (xv - mu) * rsqrtf(var + LN_EPS) * gamma[t] + beta[t];
    }
    __syncthreads();

    // ---- Phase B: xp = M@ln (threads 0..63), res = R@ln (threads 64..127) ----
    if (t < 2 * DIM) {
        const int o = t & (DIM - 1);
        const float4* Wm = reinterpret_cast<const float4*>(((t < DIM) ? M : R) + o * DIM);
        const float4* L4 = reinterpret_cast<const float4*>(ln_s);
        float acc = 0.f;
        #pragma unroll
        for (int j4 = 0; j4 < DIM / 4; ++j4) {
            float4 w = Wm[j4];
            float4 l = L4[j4];
            acc += w.x * l.x + w.y * l.y + w.z * l.z + w.w * l.w;
        }
        if (t < DIM) xp_s[o] = acc; else res_s[o] = acc;
    }
    __syncthreads();

    // ---- Phase C: Nk. Output o = t>>2; part = t&3 covers j in [16*part, 16*part+16) ----
    const float a    = TWO_PI_F * (float)kk[row];
    const int   o    = t >> 2;
    const int   part = t & 3;
    const int   j0   = part * 16;
    const float4* P4 = reinterpret_cast<const float4*>(P       + (o * DIM + j0) * NB);
    const float4* T4 = reinterpret_cast<const float4*>(periods + (o * DIM + j0) * NB);

    float acc = 0.f;
    #pragma unroll 4
    for (int jj = 0; jj < 16; ++jj) {
        float xpj = xp_s[j0 + jj];
        float4 p0 = P4[2 * jj];
        float4 p1 = P4[2 * jj + 1];
        float4 t0 = T4[2 * jj];
        float4 t1 = T4[2 * jj + 1];
        float sum =
            p0.x * __cosf(__fdividef(a, t0.x)) +
            p0.y * __cosf(__fdividef(a, t0.y)) +
            p0.z * __cosf(__fdividef(a, t0.z)) +
            p0.w * __cosf(__fdividef(a, t0.w)) +
            p1.x * __cosf(__fdividef(a, t1.x)) +
            p1.y * __cosf(__fdividef(a, t1.y)) +
            p1.z * __cosf(__fdividef(a, t1.z)) +
            p1.w * __cosf(__fdividef(a, t1.w));
        acc += xpj * sum;
    }
    // combine 4 partials (adjacent lanes o*4 .. o*4+3)
    acc += __shfl_xor(acc, 1, 64);
    acc += __shfl_xor(acc, 2, 64);
    if (part == 0) out[row * DIM + o] = res_s[o] + acc;
}

extern "C" void kernel_launch(void* const* d_in, const int* in_sizes, int n_in,
                              void* d_out, int out_size, void* d_ws, size_t ws_size,
                              hipStream_t stream)
{
    const float* x       = (const float*)d_in[0];
    const int*   kk      = (const int*)  d_in[1];
    const float* M       = (const float*)d_in[2];
    const float* R       = (const float*)d_in[3];
    const float* P       = (const float*)d_in[4];
    const float* gamma   = (const float*)d_in[5];
    const float* beta    = (const float*)d_in[6];
    const float* periods = (const float*)d_in[7];
    float* out = (float*)d_out;

    desc_fused<<<ROWS, 256, 0, stream>>>(x, kk, M, R, P, gamma, beta, periods, out);
}

// Round 2
// 79.631 us; speedup vs baseline: 1.2738x; 1.2738x over previous
//
#include <hip/hip_runtime.h>

// DescLayer fused kernel for MI355X (gfx950) — round 2.
// out[b,s,i] = res[b,s,i] + Nk[b,s,i]
//   ln   = LayerNorm(x) * gamma + beta          (biased var, eps inside sqrt)
//   xp   = ln @ M^T ; res = ln @ R^T            (M,R are [out,in] row-major)
//   Nk_i = sum_{j,g} P[i,j,g] * xp[j] * cos(2*pi*k / periods[i,j,g])
//
// Changes vs round 1 (101 us): Phase C was lane-uncoalesced (512-B lane
// stride -> 64 cache lines per load instr). Now: one block = 2 rows (halves
// P/periods L2 traffic, shares rcp(p) across rows), thread owns fixed output
// i = t>>2, 4 threads/i each reading full contiguous 32-B g-vectors; 4-lane
// groups cover whole 128-B lines. cos via native v_cos (revolutions):
// cos(2*pi*k/p) = v_cos(fract(k * rcp(p))).

constexpr int BATCH = 2;
constexpr int SEQ   = 512;
constexpr int DIM   = 64;
constexpr int NB    = 8;
constexpr int ROWS  = BATCH * SEQ;
constexpr float LN_EPS = 1e-5f;

__global__ __launch_bounds__(256) void desc_fused(
    const float* __restrict__ x,
    const int*   __restrict__ kk,
    const float* __restrict__ M,
    const float* __restrict__ R,
    const float* __restrict__ P,
    const float* __restrict__ gamma,
    const float* __restrict__ beta,
    const float* __restrict__ periods,
    float* __restrict__ out)
{
    const int r0 = blockIdx.x * 2;     // this block handles rows r0, r0+1
    const int t  = threadIdx.x;        // 0..255

    __shared__ float ln_s [2][DIM];
    __shared__ float xp_s [2][DIM];
    __shared__ float res_s[2][DIM];

    // ---- Phase A: LayerNorm, both rows (threads 0..127) ----
    if (t < 2 * DIM) {
        const int rr   = t >> 6;       // 0/1 -> row r0+rr (one wave per row)
        const int lane = t & 63;
        float xv = x[(r0 + rr) * DIM + lane];
        float s1 = xv, s2 = xv * xv;
        #pragma unroll
        for (int off = 32; off > 0; off >>= 1) {
            s1 += __shfl_xor(s1, off, 64);
            s2 += __shfl_xor(s2, off, 64);
        }
        float mu  = s1 * (1.0f / DIM);
        float var = s2 * (1.0f / DIM) - mu * mu;   // biased variance
        ln_s[rr][lane] = (xv - mu) * rsqrtf(var + LN_EPS) * gamma[lane] + beta[lane];
    }
    __syncthreads();

    // ---- Phase B: 4 wave-groups of 64: {xp r0, xp r1, res r0, res r1} ----
    {
        const int g  = t >> 6;         // 0..3
        const int rr = g & 1;
        const int o  = t & 63;
        const float4* W4 = reinterpret_cast<const float4*>(((g < 2) ? M : R) + o * DIM);
        const float4* L4 = reinterpret_cast<const float4*>(ln_s[rr]);
        float acc = 0.f;
        #pragma unroll
        for (int j4 = 0; j4 < DIM / 4; ++j4) {
            float4 w = W4[j4];
            float4 l = L4[j4];
            acc += w.x * l.x + w.y * l.y + w.z * l.z + w.w * l.w;
        }
        if (g < 2) xp_s[rr][o] = acc; else res_s[rr][o] = acc;
    }
    __syncthreads();

    // ---- Phase C: Nk for both rows. i = t>>2 fixed; part = t&3 covers
    //      j = jj*4 + part over 16 iterations; full 8-g vector per (i,j). ----
    const int   i    = t >> 2;
    const int   part = t & 3;
    const float kf0  = (float)kk[r0];
    const float kf1  = (float)kk[r0 + 1];

    float acc0 = 0.f, acc1 = 0.f;

    #pragma unroll 4
    for (int jj = 0; jj < 16; ++jj) {
        const int j    = jj * 4 + part;
        const int base = (i * DIM + j) * NB;       // float offset, 32B-aligned
        float4 p0 = *reinterpret_cast<const float4*>(P + base);
        float4 p1 = *reinterpret_cast<const float4*>(P + base + 4);
        float4 q0 = *reinterpret_cast<const float4*>(periods + base);
        float4 q1 = *reinterpret_cast<const float4*>(periods + base + 4);

        float s0 = 0.f, s1 = 0.f;
        #pragma unroll
        for (int e = 0; e < 8; ++e) {
            float pe = (e < 4) ? ((const float*)&p0)[e] : ((const float*)&p1)[e - 4];
            float qe = (e < 4) ? ((const float*)&q0)[e] : ((const float*)&q1)[e - 4];
            float rp = __builtin_amdgcn_rcpf(qe);               // 1/p
            float c0 = __builtin_amdgcn_cosf(__builtin_amdgcn_fractf(kf0 * rp));
            float c1 = __builtin_amdgcn_cosf(__builtin_amdgcn_fractf(kf1 * rp));
            s0 = fmaf(pe, c0, s0);
            s1 = fmaf(pe, c1, s1);
        }
        acc0 = fmaf(xp_s[0][j], s0, acc0);
        acc1 = fmaf(xp_s[1][j], s1, acc1);
    }

    // combine the 4 j-partials per output i (lanes 4i..4i+3, same wave)
    acc0 += __shfl_xor(acc0, 1, 64);
    acc0 += __shfl_xor(acc0, 2, 64);
    acc1 += __shfl_xor(acc1, 1, 64);
    acc1 += __shfl_xor(acc1, 2, 64);

    if (part == 0) {
        out[(r0    ) * DIM + i] = res_s[0][i] + acc0;
        out[(r0 + 1) * DIM + i] = res_s[1][i] + acc1;
    }
}

extern "C" void kernel_launch(void* const* d_in, const int* in_sizes, int n_in,
                              void* d_out, int out_size, void* d_ws, size_t ws_size,
                              hipStream_t stream)
{
    const float* x       = (const float*)d_in[0];
    const int*   kk      = (const int*)  d_in[1];
    const float* M       = (const float*)d_in[2];
    const float* R       = (const float*)d_in[3];
    const float* P       = (const float*)d_in[4];
    const float* gamma   = (const float*)d_in[5];
    const float* beta    = (const float*)d_in[6];
    const float* periods = (const float*)d_in[7];
    float* out = (float*)d_out;

    desc_fused<<<ROWS / 2, 256, 0, stream>>>(x, kk, M, R, P, gamma, beta, periods, out);
}